// Round 2
// baseline (973.343 us; speedup 1.0000x reference)
//
#include <hip/hip_runtime.h>
#include <stdint.h>

#define MM 4096   // B*S
#define KK 4096   // IN_F
#define NN 11008  // OUT_F

typedef __bf16 bf16;
typedef bf16 bf16x8 __attribute__((ext_vector_type(8)));
typedef float f32x4 __attribute__((ext_vector_type(4)));

static_assert(sizeof(bf16x8) == 16, "bf16x8 must be 16B");

// ---------------- async global->LDS (width 16) ----------------
__device__ __forceinline__ void async_ld16(const void* g, void* l) {
  __builtin_amdgcn_global_load_lds(
      (const __attribute__((address_space(1))) uint32_t*)g,
      (__attribute__((address_space(3))) uint32_t*)l,
      16, 0, 0);
}

// ---------------- weight-storage detector ----------------
// Harness contract says integer inputs land as int32; reference dtype is int8.
// Detect on-device: int32 storage => every word in [-128,127]. int8 storage =>
// 4-byte composites are out of range with probability ~1 per word.
// flag: 0 = int32 storage, 1 = int8 storage.
__global__ __launch_bounds__(256) void detect_kernel(const int* __restrict__ w,
                                                     int* __restrict__ flag) {
  __shared__ int bad;
  if (threadIdx.x == 0) bad = 0;
  __syncthreads();
  int local = 0;
  for (int i = threadIdx.x; i < 16384; i += 256) {
    int v = w[i];
    if (v < -128 || v > 127) local = 1;
  }
  if (local) atomicOr(&bad, 1);
  __syncthreads();
  if (threadIdx.x == 0) *flag = bad;
}

// ---------------- convert kernels ----------------
__global__ __launch_bounds__(256) void cvt_a_kernel(const float* __restrict__ in,
                                                    bf16* __restrict__ out, int n4) {
  int i = blockIdx.x * 256 + threadIdx.x;
  if (i >= n4) return;
  float4 v = ((const float4*)in)[i];
  union { bf16 h[4]; uint2 u; } p;
  p.h[0] = (bf16)v.x; p.h[1] = (bf16)v.y; p.h[2] = (bf16)v.z; p.h[3] = (bf16)v.w;
  ((uint2*)out)[i] = p.u;
}

// each thread produces 16 bf16 weights
__global__ __launch_bounds__(256) void cvt_w_kernel(const void* __restrict__ in,
                                                    bf16* __restrict__ out,
                                                    const int* __restrict__ flag,
                                                    int n16) {
  int i = blockIdx.x * 256 + threadIdx.x;
  if (i >= n16) return;
  bf16x8 h0, h1;
  if (*flag == 0) {
    // int32 storage: 16 int32 = 64B
    const int4* p = (const int4*)in + 4 * (size_t)i;
    int4 v0 = p[0], v1 = p[1], v2 = p[2], v3 = p[3];
    h0[0] = (bf16)(float)v0.x; h0[1] = (bf16)(float)v0.y;
    h0[2] = (bf16)(float)v0.z; h0[3] = (bf16)(float)v0.w;
    h0[4] = (bf16)(float)v1.x; h0[5] = (bf16)(float)v1.y;
    h0[6] = (bf16)(float)v1.z; h0[7] = (bf16)(float)v1.w;
    h1[0] = (bf16)(float)v2.x; h1[1] = (bf16)(float)v2.y;
    h1[2] = (bf16)(float)v2.z; h1[3] = (bf16)(float)v2.w;
    h1[4] = (bf16)(float)v3.x; h1[5] = (bf16)(float)v3.y;
    h1[6] = (bf16)(float)v3.z; h1[7] = (bf16)(float)v3.w;
  } else {
    // int8 storage: 16 int8 = 16B
    union { int4 v; int8_t b[16]; } u;
    u.v = ((const int4*)in)[i];
#pragma unroll
    for (int j = 0; j < 8; ++j) {
      h0[j] = (bf16)(float)u.b[j];
      h1[j] = (bf16)(float)u.b[j + 8];
    }
  }
  ((bf16x8*)out)[2 * (size_t)i]     = h0;
  ((bf16x8*)out)[2 * (size_t)i + 1] = h1;
}

// ---------------- shared GEMM pieces ----------------
// MFMA fragment layout (16x16x32 bf16):
//   A: lane holds A[m=lane&15][k=(lane>>4)*8 + 0..7]
//   B: lane holds B[n=lane&15][k=(lane>>4)*8 + 0..7]
//   C/D: col=lane&15, row=(lane>>4)*4 + reg   [measured: learn_hip m89]
__device__ __forceinline__ void mfma_step(const bf16* As, const bf16* Ws,
                                          int lane, int wr, int wc, f32x4 acc[4][4]) {
  const int m16 = lane & 15;
  const int ko  = (lane >> 4) * 8;
  bf16x8 af[4], bg[4];
#pragma unroll
  for (int t = 0; t < 4; ++t) {
    af[t] = *(const bf16x8*)(As + (wr * 64 + t * 16 + m16) * 32 + ko);
    bg[t] = *(const bf16x8*)(Ws + (wc * 64 + t * 16 + m16) * 32 + ko);
  }
#pragma unroll
  for (int tm = 0; tm < 4; ++tm)
#pragma unroll
    for (int tn = 0; tn < 4; ++tn)
      acc[tm][tn] = __builtin_amdgcn_mfma_f32_16x16x32_bf16(af[tm], bg[tn], acc[tm][tn], 0, 0, 0);
}

__device__ __forceinline__ void epilogue(f32x4 acc[4][4],
                                         const float* __restrict__ scales,
                                         const float* __restrict__ bias,
                                         float* __restrict__ out,
                                         int bm, int bn, int lane, int wr, int wc) {
  const int row0 = bm * 128 + wr * 64 + ((lane >> 4) * 4);
  const int col0 = bn * 128 + wc * 64 + (lane & 15);
#pragma unroll
  for (int tn = 0; tn < 4; ++tn) {
    const int col = col0 + tn * 16;
    const float s = scales[col];
    const float b = bias[col];
#pragma unroll
    for (int tm = 0; tm < 4; ++tm) {
      const int r0 = row0 + tm * 16;
#pragma unroll
      for (int r = 0; r < 4; ++r)
        out[(long)(r0 + r) * NN + col] = acc[tm][tn][r] * s + b;
    }
  }
}

// ---------------- fast path: bf16 x bf16 (preconverted), m97 structure ----------------
__global__ __launch_bounds__(256, 2) void gemm_bf16_kernel(
    const bf16* __restrict__ A,   // [MM][KK] bf16
    const bf16* __restrict__ W,   // [NN][KK] bf16 (B^T layout)
    const float* __restrict__ scales,
    const float* __restrict__ bias,
    float* __restrict__ out) {
  __shared__ bf16 As[128 * 32];
  __shared__ bf16 Ws[128 * 32];
  const int tid  = threadIdx.x;
  const int lane = tid & 63;
  const int wave = tid >> 6;
  const int wr   = wave >> 1, wc = wave & 1;
  const int bn   = blockIdx.x, bm = blockIdx.y;

  f32x4 acc[4][4] = {};

  const bf16* Ab = A + (long)bm * 128 * KK;
  const bf16* Wb = W + (long)bn * 128 * KK;

  for (int k0 = 0; k0 < KK; k0 += 32) {
    __syncthreads();  // prior LDS reads done before overwrite
#pragma unroll
    for (int j = 0; j < 2; ++j) {
      const int c = j * 256 + tid;  // 16B-chunk index: row=c>>2, koff=(c&3)*8
      async_ld16(Ab + (long)(c >> 2) * KK + k0 + (c & 3) * 8,
                 As + j * 2048 + wave * 512);  // wave-uniform base; HW adds lane*16B
      async_ld16(Wb + (long)(c >> 2) * KK + k0 + (c & 3) * 8,
                 Ws + j * 2048 + wave * 512);
    }
    __syncthreads();  // drains vmcnt: tiles visible
    mfma_step(As, Ws, lane, wr, wc, acc);
  }
  epilogue(acc, scales, bias, out, bm, bn, lane, wr, wc);
}

// ---------------- fallback: fused convert-in-staging (if ws too small) ----------------
__global__ __launch_bounds__(256, 2) void gemm_fused_kernel(
    const float* __restrict__ A,   // [MM][KK] fp32
    const void* __restrict__ Wraw, // [NN][KK] int32 or int8 per flag
    const float* __restrict__ scales,
    const float* __restrict__ bias,
    float* __restrict__ out,
    const int* __restrict__ flag) {
  __shared__ bf16 As[128 * 32];
  __shared__ bf16 Ws[128 * 32];
  const int tid  = threadIdx.x;
  const int lane = tid & 63;
  const int wave = tid >> 6;
  const int wr   = wave >> 1, wc = wave & 1;
  const int bn   = blockIdx.x, bm = blockIdx.y;
  const int f    = *flag;

  f32x4 acc[4][4] = {};

  const int r    = tid >> 1;         // 0..127: row in tile
  const int kk16 = (tid & 1) * 16;   // half-row

  const float* Ag = A + (long)(bm * 128 + r) * KK + kk16;
  const long woff = (long)(bn * 128 + r) * KK + kk16;
  bf16* Asw = As + r * 32 + kk16;
  bf16* Wsw = Ws + r * 32 + kk16;

  for (int k0 = 0; k0 < KK; k0 += 32) {
    float4 a0 = *(const float4*)(Ag + k0);
    float4 a1 = *(const float4*)(Ag + k0 + 4);
    float4 a2 = *(const float4*)(Ag + k0 + 8);
    float4 a3 = *(const float4*)(Ag + k0 + 12);
    bf16x8 w0, w1;
    if (f == 0) {
      const int4* p = (const int4*)Wraw + ((woff + k0) >> 2);
      int4 v0 = p[0], v1 = p[1], v2 = p[2], v3 = p[3];
      w0[0] = (bf16)(float)v0.x; w0[1] = (bf16)(float)v0.y;
      w0[2] = (bf16)(float)v0.z; w0[3] = (bf16)(float)v0.w;
      w0[4] = (bf16)(float)v1.x; w0[5] = (bf16)(float)v1.y;
      w0[6] = (bf16)(float)v1.z; w0[7] = (bf16)(float)v1.w;
      w1[0] = (bf16)(float)v2.x; w1[1] = (bf16)(float)v2.y;
      w1[2] = (bf16)(float)v2.z; w1[3] = (bf16)(float)v2.w;
      w1[4] = (bf16)(float)v3.x; w1[5] = (bf16)(float)v3.y;
      w1[6] = (bf16)(float)v3.z; w1[7] = (bf16)(float)v3.w;
    } else {
      union { int4 v; int8_t b[16]; } u;
      u.v = *(const int4*)((const int8_t*)Wraw + woff + k0);
#pragma unroll
      for (int j = 0; j < 8; ++j) {
        w0[j] = (bf16)(float)u.b[j];
        w1[j] = (bf16)(float)u.b[j + 8];
      }
    }
    __syncthreads();
    bf16x8 h0, h1;
    h0[0] = (bf16)a0.x; h0[1] = (bf16)a0.y; h0[2] = (bf16)a0.z; h0[3] = (bf16)a0.w;
    h0[4] = (bf16)a1.x; h0[5] = (bf16)a1.y; h0[6] = (bf16)a1.z; h0[7] = (bf16)a1.w;
    h1[0] = (bf16)a2.x; h1[1] = (bf16)a2.y; h1[2] = (bf16)a2.z; h1[3] = (bf16)a2.w;
    h1[4] = (bf16)a3.x; h1[5] = (bf16)a3.y; h1[6] = (bf16)a3.z; h1[7] = (bf16)a3.w;
    *(bf16x8*)(Asw)     = h0;
    *(bf16x8*)(Asw + 8) = h1;
    *(bf16x8*)(Wsw)     = w0;
    *(bf16x8*)(Wsw + 8) = w1;
    __syncthreads();
    mfma_step(As, Ws, lane, wr, wc, acc);
  }
  epilogue(acc, scales, bias, out, bm, bn, lane, wr, wc);
}

// ---------------- launch ----------------
extern "C" void kernel_launch(void* const* d_in, const int* in_sizes, int n_in,
                              void* d_out, int out_size, void* d_ws, size_t ws_size,
                              hipStream_t stream) {
  const float* x      = (const float*)d_in[0];
  const void*  w8     = d_in[1];  // int32 (harness contract) or int8 (detected)
  const float* scales = (const float*)d_in[2];
  const float* bias   = (const float*)d_in[3];
  float*       out    = (float*)d_out;

  const size_t A_BYTES = (size_t)MM * KK * 2;  // 32 MiB
  const size_t W_BYTES = (size_t)NN * KK * 2;  // 86 MiB
  const size_t F_BYTES = 256;                  // flag slot
  dim3 grid(NN / 128, MM / 128);               // 86 x 32 = 2752 blocks

  if (ws_size >= A_BYTES + W_BYTES + F_BYTES) {
    bf16* A16 = (bf16*)d_ws;
    bf16* W16 = (bf16*)((char*)d_ws + A_BYTES);
    int*  flg = (int*)((char*)d_ws + A_BYTES + W_BYTES);
    hipLaunchKernelGGL(detect_kernel, dim3(1), dim3(256), 0, stream, (const int*)w8, flg);
    const int n4 = MM * KK / 4;
    hipLaunchKernelGGL(cvt_a_kernel, dim3((n4 + 255) / 256), dim3(256), 0, stream, x, A16, n4);
    const int n16 = NN * KK / 16;
    hipLaunchKernelGGL(cvt_w_kernel, dim3((n16 + 255) / 256), dim3(256), 0, stream, w8, W16, flg, n16);
    hipLaunchKernelGGL(gemm_bf16_kernel, grid, dim3(256), 0, stream, A16, W16, scales, bias, out);
  } else {
    int* flg = (int*)d_ws;  // assume at least 4 bytes of ws
    hipLaunchKernelGGL(detect_kernel, dim3(1), dim3(256), 0, stream, (const int*)w8, flg);
    hipLaunchKernelGGL(gemm_fused_kernel, grid, dim3(256), 0, stream, x, w8, scales, bias, out, flg);
  }
}

// Round 3
// 748.756 us; speedup vs baseline: 1.2999x; 1.2999x over previous
//
#include <hip/hip_runtime.h>
#include <stdint.h>

#define MM 4096   // B*S
#define KK 4096   // IN_F
#define NN 11008  // OUT_F

typedef __bf16 bf16;
typedef bf16 bf16x8 __attribute__((ext_vector_type(8)));
typedef float f32x4 __attribute__((ext_vector_type(4)));

static_assert(sizeof(bf16x8) == 16, "bf16x8 must be 16B");

// ---------------- async global->LDS (width 16) ----------------
__device__ __forceinline__ void async_ld16(const void* g, void* l) {
  __builtin_amdgcn_global_load_lds(
      (const __attribute__((address_space(1))) uint32_t*)g,
      (__attribute__((address_space(3))) uint32_t*)l,
      16, 0, 0);
}

// ---------------- convert kernels ----------------
__global__ __launch_bounds__(256) void cvt_a_kernel(const float* __restrict__ in,
                                                    bf16* __restrict__ out, int n4) {
  int i = blockIdx.x * 256 + threadIdx.x;
  if (i >= n4) return;
  float4 v = ((const float4*)in)[i];
  union { bf16 h[4]; uint2 u; } p;
  p.h[0] = (bf16)v.x; p.h[1] = (bf16)v.y; p.h[2] = (bf16)v.z; p.h[3] = (bf16)v.w;
  ((uint2*)out)[i] = p.u;
}

// weights land as int32 (harness integer contract; confirmed by R2 absmax=256).
// thread i: 16B int4 load (4 int32) -> 8B bf16x4 store. Fully coalesced.
__global__ __launch_bounds__(256) void cvt_w_kernel(const int* __restrict__ in,
                                                    bf16* __restrict__ out, int n4) {
  int i = blockIdx.x * 256 + threadIdx.x;
  if (i >= n4) return;
  int4 v = ((const int4*)in)[i];
  union { bf16 h[4]; uint2 u; } p;
  p.h[0] = (bf16)(float)v.x; p.h[1] = (bf16)(float)v.y;
  p.h[2] = (bf16)(float)v.z; p.h[3] = (bf16)(float)v.w;
  ((uint2*)out)[i] = p.u;
}

// ---------------- shared GEMM pieces ----------------
// MFMA fragment layout (16x16x32 bf16):
//   A: lane holds A[m=lane&15][k=(lane>>4)*8 + 0..7]
//   B: lane holds B[n=lane&15][k=(lane>>4)*8 + 0..7]
//   C/D: col=lane&15, row=(lane>>4)*4 + reg   [measured: learn_hip m89]
//
// LDS tile layout (128 rows x 32 k, bf16): row r occupies 64B = 4 16B-chunks.
// k-chunk k of row r is stored at slot j = (k + (r>>1)) & 3  (XOR/rotate
// swizzle). Without it, ds_read_b128's 16-lane issue groups (k uniform per
// group) land on 2 bank-quads via row parity -> 8-way conflict
// (SQ_LDS_BANK_CONFLICT=4.5e7 in R2). With it: 2-way, free (m136).
__device__ __forceinline__ void mfma_step(const bf16* As, const bf16* Ws,
                                          int lane, int wr, int wc, f32x4 acc[4][4]) {
  const int m16 = lane & 15;
  const int k   = lane >> 4;                 // k-chunk 0..3
  const int jj  = (k + (m16 >> 1)) & 3;      // swizzled slot (t*16,wr*64 are ≡0 mod 8 rows)
  bf16x8 af[4], bg[4];
#pragma unroll
  for (int t = 0; t < 4; ++t) {
    af[t] = *(const bf16x8*)(As + (wr * 64 + t * 16 + m16) * 32 + jj * 8);
    bg[t] = *(const bf16x8*)(Ws + (wc * 64 + t * 16 + m16) * 32 + jj * 8);
  }
#pragma unroll
  for (int tm = 0; tm < 4; ++tm)
#pragma unroll
    for (int tn = 0; tn < 4; ++tn)
      acc[tm][tn] = __builtin_amdgcn_mfma_f32_16x16x32_bf16(af[tm], bg[tn], acc[tm][tn], 0, 0, 0);
}

__device__ __forceinline__ void epilogue(f32x4 acc[4][4],
                                         const float* __restrict__ scales,
                                         const float* __restrict__ bias,
                                         float* __restrict__ out,
                                         int bm, int bn, int lane, int wr, int wc) {
  const int row0 = bm * 128 + wr * 64 + ((lane >> 4) * 4);
  const int col0 = bn * 128 + wc * 64 + (lane & 15);
#pragma unroll
  for (int tn = 0; tn < 4; ++tn) {
    const int col = col0 + tn * 16;
    const float s = scales[col];
    const float b = bias[col];
#pragma unroll
    for (int tm = 0; tm < 4; ++tm) {
      const int r0 = row0 + tm * 16;
#pragma unroll
      for (int r = 0; r < 4; ++r)
        out[(long)(r0 + r) * NN + col] = acc[tm][tn][r] * s + b;
    }
  }
}

// ---------------- fast path: bf16 x bf16 (preconverted), m97 structure ----------------
// grid(32, 86): bm = blockIdx.x (FASTEST-varying). Concurrent blocks share a
// narrow bn window -> A (32 MiB) stays LLC-resident across all 86 bn sweeps
// and W (86 MiB) streams from HBM exactly once. R2's bn-fastest mapping
// fetched 2.07 GiB from HBM (A re-streamed per bm-group) -> HBM-traffic-bound.
__global__ __launch_bounds__(256, 2) void gemm_bf16_kernel(
    const bf16* __restrict__ A,   // [MM][KK] bf16
    const bf16* __restrict__ W,   // [NN][KK] bf16 (B^T layout)
    const float* __restrict__ scales,
    const float* __restrict__ bias,
    float* __restrict__ out) {
  __shared__ bf16 As[128 * 32];
  __shared__ bf16 Ws[128 * 32];
  const int tid  = threadIdx.x;
  const int lane = tid & 63;
  const int wave = tid >> 6;
  const int wr   = wave >> 1, wc = wave & 1;
  const int bm   = blockIdx.x, bn = blockIdx.y;

  f32x4 acc[4][4] = {};

  const bf16* Ab = A + (long)bm * 128 * KK;
  const bf16* Wb = W + (long)bn * 128 * KK;

  for (int k0 = 0; k0 < KK; k0 += 32) {
    __syncthreads();  // prior LDS reads done before overwrite
#pragma unroll
    for (int j2 = 0; j2 < 2; ++j2) {
      const int c = j2 * 256 + tid;          // LDS 16B-slot index
      const int r = c >> 2;                  // row 0..127
      const int j = c & 3;                   // slot within row
      const int k = (j - (r >> 1)) & 3;      // global k-chunk stored here (swizzle inverse)
      const long goff = (long)r * KK + k0 + k * 8;
      async_ld16(Ab + goff, As + j2 * 2048 + wave * 512);  // wave-uniform base; HW adds lane*16B
      async_ld16(Wb + goff, Ws + j2 * 2048 + wave * 512);
    }
    __syncthreads();  // drains vmcnt: tiles visible
    mfma_step(As, Ws, lane, wr, wc, acc);
  }
  epilogue(acc, scales, bias, out, bm, bn, lane, wr, wc);
}

// ---------------- fallback: fused convert-in-staging (if ws too small) ----------------
__global__ __launch_bounds__(256, 2) void gemm_fused_kernel(
    const float* __restrict__ A,   // [MM][KK] fp32
    const int* __restrict__ W32,   // [NN][KK] int32
    const float* __restrict__ scales,
    const float* __restrict__ bias,
    float* __restrict__ out) {
  __shared__ bf16 As[128 * 32];
  __shared__ bf16 Ws[128 * 32];
  const int tid  = threadIdx.x;
  const int lane = tid & 63;
  const int wave = tid >> 6;
  const int wr   = wave >> 1, wc = wave & 1;
  const int bm   = blockIdx.x, bn = blockIdx.y;

  f32x4 acc[4][4] = {};

  const int r    = tid >> 1;         // 0..127: row in tile
  const int kk16 = (tid & 1) * 16;   // half-row

  const float* Ag = A + (long)(bm * 128 + r) * KK + kk16;
  const int*   Wg = W32 + (long)(bn * 128 + r) * KK + kk16;
  bf16* Asw = As + r * 32 + kk16;
  bf16* Wsw = Ws + r * 32 + kk16;

  for (int k0 = 0; k0 < KK; k0 += 32) {
    float4 a0 = *(const float4*)(Ag + k0);
    float4 a1 = *(const float4*)(Ag + k0 + 4);
    float4 a2 = *(const float4*)(Ag + k0 + 8);
    float4 a3 = *(const float4*)(Ag + k0 + 12);
    int4 v0 = *(const int4*)(Wg + k0);
    int4 v1 = *(const int4*)(Wg + k0 + 4);
    int4 v2 = *(const int4*)(Wg + k0 + 8);
    int4 v3 = *(const int4*)(Wg + k0 + 12);
    __syncthreads();
    bf16x8 h0, h1, w0, w1;
    h0[0] = (bf16)a0.x; h0[1] = (bf16)a0.y; h0[2] = (bf16)a0.z; h0[3] = (bf16)a0.w;
    h0[4] = (bf16)a1.x; h0[5] = (bf16)a1.y; h0[6] = (bf16)a1.z; h0[7] = (bf16)a1.w;
    h1[0] = (bf16)a2.x; h1[1] = (bf16)a2.y; h1[2] = (bf16)a2.z; h1[3] = (bf16)a2.w;
    h1[4] = (bf16)a3.x; h1[5] = (bf16)a3.y; h1[6] = (bf16)a3.z; h1[7] = (bf16)a3.w;
    w0[0] = (bf16)(float)v0.x; w0[1] = (bf16)(float)v0.y;
    w0[2] = (bf16)(float)v0.z; w0[3] = (bf16)(float)v0.w;
    w0[4] = (bf16)(float)v1.x; w0[5] = (bf16)(float)v1.y;
    w0[6] = (bf16)(float)v1.z; w0[7] = (bf16)(float)v1.w;
    w1[0] = (bf16)(float)v2.x; w1[1] = (bf16)(float)v2.y;
    w1[2] = (bf16)(float)v2.z; w1[3] = (bf16)(float)v2.w;
    w1[4] = (bf16)(float)v3.x; w1[5] = (bf16)(float)v3.y;
    w1[6] = (bf16)(float)v3.z; w1[7] = (bf16)(float)v3.w;
    *(bf16x8*)(Asw)     = h0;
    *(bf16x8*)(Asw + 8) = h1;
    *(bf16x8*)(Wsw)     = w0;
    *(bf16x8*)(Wsw + 8) = w1;
    __syncthreads();
    // no swizzle in this path: plain layout, jj == k
    const int m16 = lane & 15;
    const int ko  = (lane >> 4) * 8;
    bf16x8 af[4], bg[4];
#pragma unroll
    for (int t = 0; t < 4; ++t) {
      af[t] = *(const bf16x8*)(As + (wr * 64 + t * 16 + m16) * 32 + ko);
      bg[t] = *(const bf16x8*)(Ws + (wc * 64 + t * 16 + m16) * 32 + ko);
    }
#pragma unroll
    for (int tm = 0; tm < 4; ++tm)
#pragma unroll
      for (int tn = 0; tn < 4; ++tn)
        acc[tm][tn] = __builtin_amdgcn_mfma_f32_16x16x32_bf16(af[tm], bg[tn], acc[tm][tn], 0, 0, 0);
  }
  epilogue(acc, scales, bias, out, bm, bn, lane, wr, wc);
}

// ---------------- launch ----------------
extern "C" void kernel_launch(void* const* d_in, const int* in_sizes, int n_in,
                              void* d_out, int out_size, void* d_ws, size_t ws_size,
                              hipStream_t stream) {
  const float* x      = (const float*)d_in[0];
  const int*   w32    = (const int*)d_in[1];  // integer input -> int32 storage (confirmed R2)
  const float* scales = (const float*)d_in[2];
  const float* bias   = (const float*)d_in[3];
  float*       out    = (float*)d_out;

  const size_t A_BYTES = (size_t)MM * KK * 2;  // 32 MiB
  const size_t W_BYTES = (size_t)NN * KK * 2;  // 86 MiB
  dim3 grid(MM / 128, NN / 128);               // bm fastest: 32 x 86

  if (ws_size >= A_BYTES + W_BYTES) {
    bf16* A16 = (bf16*)d_ws;
    bf16* W16 = (bf16*)((char*)d_ws + A_BYTES);
    const int na = MM * KK / 4;
    hipLaunchKernelGGL(cvt_a_kernel, dim3((na + 255) / 256), dim3(256), 0, stream, x, A16, na);
    const int nw = NN * KK / 4;
    hipLaunchKernelGGL(cvt_w_kernel, dim3((nw + 255) / 256), dim3(256), 0, stream, w32, W16, nw);
    hipLaunchKernelGGL(gemm_bf16_kernel, grid, dim3(256), 0, stream, A16, W16, scales, bias, out);
  } else {
    hipLaunchKernelGGL(gemm_fused_kernel, grid, dim3(256), 0, stream, x, w32, scales, bias, out);
  }
}